// Round 6
// baseline (206.932 us; speedup 1.0000x reference)
//
#include <hip/hip_runtime.h>

#define N_NODES 100000
#define N_EDGES 1600000

typedef __attribute__((ext_vector_type(8))) short short8;
typedef __attribute__((ext_vector_type(4))) float f32x4;
typedef __attribute__((ext_vector_type(2))) unsigned short ushort2v;
typedef __attribute__((ext_vector_type(4))) unsigned short ushort4v;
typedef __attribute__((ext_vector_type(8))) unsigned short ushort8v;

static __device__ inline unsigned short f2bf(float f) {
    union { float f; unsigned u; } v; v.f = f;
    unsigned r = v.u + 0x7FFF + ((v.u >> 16) & 1);   // round-to-nearest-even
    return (unsigned short)(r >> 16);
}
static __device__ inline float bf2f(unsigned short u) {
    union { unsigned u; float f; } v; v.u = ((unsigned)u) << 16;
    return v.f;
}

// ---------------- row_ptr via binary search over sorted dst ----------------
__global__ __launch_bounds__(256) void rowptr_k(const int* __restrict__ dst,
                                                int* __restrict__ rp) {
    int t = blockIdx.x * blockDim.x + threadIdx.x;
    if (t > N_NODES) return;
    int lo = 0, hi = N_EDGES;
    while (lo < hi) {
        int mid = (lo + hi) >> 1;
        if (dst[mid] < t) lo = mid + 1; else hi = mid;
    }
    rp[t] = lo;
}

// ---------------- weight prep: transpose + bf16 ----------------------------
__global__ __launch_bounds__(256) void prep_k(const float* __restrict__ w1,
                                              const float* __restrict__ w2,
                                              const float* __restrict__ l0w,
                                              unsigned short* __restrict__ w1t,
                                              unsigned short* __restrict__ w2t,
                                              unsigned short* __restrict__ w0t) {
    int id = blockIdx.x * blockDim.x + threadIdx.x;
    if (id < 128 * 160) {
        int o = id / 160, k = id - o * 160;
        w1t[id] = (k < 144) ? f2bf(w1[k * 128 + o]) : (unsigned short)0;
    } else if (id < 128 * 160 + 64 * 128) {
        int j = id - 128 * 160;
        int o = j / 128, k = j - o * 128;
        w2t[j] = f2bf(w2[k * 64 + o]);
    } else if (id < 128 * 160 + 64 * 128 + 80 * 64) {
        int j = id - 128 * 160 - 64 * 128;
        int o = j / 64, k = j - o * 64;
        w0t[j] = (o < 72 && k < 36) ? f2bf(l0w[k * 72 + o]) : (unsigned short)0;
    }
}

template<int VEC> struct VecU;
template<> struct VecU<1> { using T = unsigned short; };
template<> struct VecU<2> { using T = ushort2v; };
template<> struct VecU<4> { using T = ushort4v; };
template<> struct VecU<8> { using T = ushort8v; };

// ---------------- conv1: f32 in [N][3] -> bf16 out -------------------------
template<int OUT_STRIDE>
__global__ __launch_bounds__(256) void conv1_k(const float* __restrict__ hin,
                                               const float* __restrict__ kv,
                                               const int* __restrict__ src,
                                               const int* __restrict__ rp,
                                               unsigned short* __restrict__ hout) {
    int id = blockIdx.x * blockDim.x + threadIdx.x;
    if (id >= N_NODES * 3) return;
    int t = id / 3;
    int c = id - t * 3;
    int e0 = rp[t], e1 = rp[t + 1];
    float a0 = 0.f, a1 = 0.f;
    int e = e0;
    for (; e + 8 <= e1; e += 8) {
        int s[8]; float k0[8], k1[8], v[8];
#pragma unroll
        for (int u = 0; u < 8; ++u) s[u]  = src[e + u];
#pragma unroll
        for (int u = 0; u < 8; ++u) k0[u] = kv[e + u];
#pragma unroll
        for (int u = 0; u < 8; ++u) k1[u] = kv[N_EDGES + e + u];
#pragma unroll
        for (int u = 0; u < 8; ++u) v[u]  = hin[(size_t)s[u] * 3 + c];
#pragma unroll
        for (int u = 0; u < 8; ++u) { a0 += k0[u] * v[u]; a1 += k1[u] * v[u]; }
    }
    for (; e < e1; ++e) {
        int s = src[e];
        float v = hin[(size_t)s * 3 + c];
        a0 += kv[e] * v;
        a1 += kv[N_EDGES + e] * v;
    }
    hout[(size_t)t * OUT_STRIDE + c]     = f2bf(a0);
    hout[(size_t)t * OUT_STRIDE + 3 + c] = f2bf(a1);
}

// ---------------- bf16 aniso conv (conv2/conv3) ----------------------------
template<int C, int VEC, int IN_STRIDE, int OUT_STRIDE, int OUT_OFF,
         int PAD_FROM, int PAD_TO>
__global__ __launch_bounds__(256) void convb_k(const unsigned short* __restrict__ hin,
                                               const float* __restrict__ kv,
                                               const int* __restrict__ src,
                                               const int* __restrict__ rp,
                                               unsigned short* __restrict__ hout) {
    constexpr int G = C / VEC;
    using VT = typename VecU<VEC>::T;
    int id = blockIdx.x * blockDim.x + threadIdx.x;
    if (id >= N_NODES * G) return;
    int t = id / G;
    int g = id - t * G;
    int c0 = g * VEC;
    int e0 = rp[t], e1 = rp[t + 1];

    float a0[VEC], a1[VEC];
#pragma unroll
    for (int q = 0; q < VEC; ++q) { a0[q] = 0.f; a1[q] = 0.f; }

    int e = e0;
    for (; e + 8 <= e1; e += 8) {
        int s[8]; float k0[8], k1[8];
#pragma unroll
        for (int u = 0; u < 8; ++u) s[u]  = src[e + u];
#pragma unroll
        for (int u = 0; u < 8; ++u) k0[u] = kv[e + u];
#pragma unroll
        for (int u = 0; u < 8; ++u) k1[u] = kv[N_EDGES + e + u];
        VT v[8];
#pragma unroll
        for (int u = 0; u < 8; ++u)
            v[u] = *reinterpret_cast<const VT*>(hin + (size_t)s[u] * IN_STRIDE + c0);
#pragma unroll
        for (int u = 0; u < 8; ++u) {
            const unsigned short* vf = reinterpret_cast<const unsigned short*>(&v[u]);
#pragma unroll
            for (int q = 0; q < VEC; ++q) {
                float x = bf2f(vf[q]);
                a0[q] += k0[u] * x;
                a1[q] += k1[u] * x;
            }
        }
    }
    for (; e < e1; ++e) {
        int s = src[e];
        float k0 = kv[e], k1 = kv[N_EDGES + e];
        VT v = *reinterpret_cast<const VT*>(hin + (size_t)s * IN_STRIDE + c0);
        const unsigned short* vf = reinterpret_cast<const unsigned short*>(&v);
#pragma unroll
        for (int q = 0; q < VEC; ++q) {
            float x = bf2f(vf[q]);
            a0[q] += k0 * x;
            a1[q] += k1 * x;
        }
    }

    VT r0, r1;
    unsigned short* r0f = reinterpret_cast<unsigned short*>(&r0);
    unsigned short* r1f = reinterpret_cast<unsigned short*>(&r1);
#pragma unroll
    for (int q = 0; q < VEC; ++q) { r0f[q] = f2bf(a0[q]); r1f[q] = f2bf(a1[q]); }
    *reinterpret_cast<VT*>(hout + (size_t)t * OUT_STRIDE + OUT_OFF + c0)     = r0;
    *reinterpret_cast<VT*>(hout + (size_t)t * OUT_STRIDE + OUT_OFF + C + c0) = r1;

    if constexpr (PAD_TO > PAD_FROM) {
        if (g == G - 1) {
            ushort4v z = {0, 0, 0, 0};
#pragma unroll
            for (int j = PAD_FROM; j < PAD_TO; j += 4)
                *reinterpret_cast<ushort4v*>(hout + (size_t)t * OUT_STRIDE + j) = z;
        }
    }
}

// ---------------- lin0 via MFMA: h4b = relu(h3b[N][64] @ w0t + b0) ---------
__global__ __launch_bounds__(256) void lin0m_k(const unsigned short* __restrict__ h3b,
                                               const unsigned short* __restrict__ w0t,
                                               const float* __restrict__ b0,
                                               unsigned short* __restrict__ h4b) {
    int tid = threadIdx.x;
    int w = tid >> 6;
    int lane = tid & 63;
    int lr = lane & 15;
    int kg = lane >> 4;
    int row_base = blockIdx.x * 64 + w * 16;

    f32x4 acc[5];
#pragma unroll
    for (int n = 0; n < 5; ++n) acc[n] = (f32x4){0.f, 0.f, 0.f, 0.f};

    const unsigned short* arow = h3b + (size_t)(row_base + lr) * 64 + kg * 8;
#pragma unroll
    for (int ks = 0; ks < 2; ++ks) {
        short8 a = *reinterpret_cast<const short8*>(arow + ks * 32);
#pragma unroll
        for (int n = 0; n < 5; ++n) {
            short8 b = *reinterpret_cast<const short8*>(w0t + (n * 16 + lr) * 64 + ks * 32 + kg * 8);
            acc[n] = __builtin_amdgcn_mfma_f32_16x16x32_bf16(a, b, acc[n], 0, 0, 0);
        }
    }
#pragma unroll
    for (int n = 0; n < 5; ++n) {
        int col = n * 16 + lr;
        if (col < 72) {
            float bv = b0[col];
#pragma unroll
            for (int q = 0; q < 4; ++q) {
                int t = row_base + kg * 4 + q;
                if (t < N_NODES)
                    h4b[(size_t)t * 72 + col] = f2bf(fmaxf(acc[n][q] + bv, 0.f));
            }
        }
    }
}

// ---------------- fused conv4 + MLP head + L2 normalize --------------------
// Block = 256 thr (4 waves), 64 nodes. Phase A: gather-conv h4b rows into LDS
// h5 tile [64][FH]. Phase B: MFMA stage1 (A from LDS) -> shid. Phase C: MFMA
// stage2 + bias + L2-normalize -> out.
#define FH 168
#define HSTRIDE 136
__global__ __launch_bounds__(256) void fused_k(const unsigned short* __restrict__ h4b,
                                               const float* __restrict__ kv,
                                               const int* __restrict__ src,
                                               const int* __restrict__ rp,
                                               const unsigned short* __restrict__ w1t,
                                               const float* __restrict__ b1,
                                               const unsigned short* __restrict__ w2t,
                                               const float* __restrict__ b2,
                                               float* __restrict__ out) {
    __shared__ unsigned short sh[64 * FH];
    __shared__ unsigned short shid[64 * HSTRIDE];
    int tid = threadIdx.x;
    int node0 = blockIdx.x * 64;

    // ---- phase A: gather conv4 into sh; 576 tasks = node*9 + g ----
    for (int task = tid; task < 576; task += 256) {
        int nd = task / 9;
        int g  = task - nd * 9;
        int t  = node0 + nd;
        int c0 = g * 8;
        int e0 = 0, e1 = 0;
        if (t < N_NODES) { e0 = rp[t]; e1 = rp[t + 1]; }

        float a0[8], a1[8];
#pragma unroll
        for (int q = 0; q < 8; ++q) { a0[q] = 0.f; a1[q] = 0.f; }

        int e = e0;
        for (; e + 8 <= e1; e += 8) {
            int s[8]; float k0[8], k1[8];
#pragma unroll
            for (int u = 0; u < 8; ++u) s[u]  = src[e + u];
#pragma unroll
            for (int u = 0; u < 8; ++u) k0[u] = kv[e + u];
#pragma unroll
            for (int u = 0; u < 8; ++u) k1[u] = kv[N_EDGES + e + u];
            ushort8v v[8];
#pragma unroll
            for (int u = 0; u < 8; ++u)
                v[u] = *reinterpret_cast<const ushort8v*>(h4b + (size_t)s[u] * 72 + c0);
#pragma unroll
            for (int u = 0; u < 8; ++u) {
#pragma unroll
                for (int q = 0; q < 8; ++q) {
                    float x = bf2f(v[u][q]);
                    a0[q] += k0[u] * x;
                    a1[q] += k1[u] * x;
                }
            }
        }
        for (; e < e1; ++e) {
            int s = src[e];
            float k0 = kv[e], k1 = kv[N_EDGES + e];
            ushort8v v = *reinterpret_cast<const ushort8v*>(h4b + (size_t)s * 72 + c0);
#pragma unroll
            for (int q = 0; q < 8; ++q) {
                float x = bf2f(v[q]);
                a0[q] += k0 * x;
                a1[q] += k1 * x;
            }
        }

        ushort8v r0, r1;
#pragma unroll
        for (int q = 0; q < 8; ++q) { r0[q] = f2bf(a0[q]); r1[q] = f2bf(a1[q]); }
        *reinterpret_cast<ushort8v*>(sh + nd * FH + c0)      = r0;
        *reinterpret_cast<ushort8v*>(sh + nd * FH + 72 + c0) = r1;
    }
    // zero K-pad cols 144..159
    for (int i = tid; i < 128; i += 256) {
        int nd = i >> 1, half = i & 1;
        ushort8v z = {0, 0, 0, 0, 0, 0, 0, 0};
        *reinterpret_cast<ushort8v*>(sh + nd * FH + 144 + half * 8) = z;
    }
    __syncthreads();

    // ---- phase B: stage 1 MFMA (A from LDS) ----
    int w = tid >> 6;
    int lane = tid & 63;
    int lr = lane & 15;
    int kg = lane >> 4;
    int row_base = node0 + w * 16;

    f32x4 acc[8];
#pragma unroll
    for (int n = 0; n < 8; ++n) acc[n] = (f32x4){0.f, 0.f, 0.f, 0.f};

    const unsigned short* arow = sh + (w * 16 + lr) * FH + kg * 8;
#pragma unroll
    for (int ks = 0; ks < 5; ++ks) {
        short8 a = *reinterpret_cast<const short8*>(arow + ks * 32);
#pragma unroll
        for (int n = 0; n < 8; ++n) {
            short8 b = *reinterpret_cast<const short8*>(w1t + (n * 16 + lr) * 160 + ks * 32 + kg * 8);
            acc[n] = __builtin_amdgcn_mfma_f32_16x16x32_bf16(a, b, acc[n], 0, 0, 0);
        }
    }
#pragma unroll
    for (int n = 0; n < 8; ++n) {
        float bv = b1[n * 16 + lr];
#pragma unroll
        for (int q = 0; q < 4; ++q) {
            float hv = fmaxf(acc[n][q] + bv, 0.f);
            shid[(w * 16 + kg * 4 + q) * HSTRIDE + n * 16 + lr] = f2bf(hv);
        }
    }
    __syncthreads();

    // ---- phase C: stage 2 MFMA + bias + normalize ----
    f32x4 acc2[4];
#pragma unroll
    for (int n = 0; n < 4; ++n) acc2[n] = (f32x4){0.f, 0.f, 0.f, 0.f};
#pragma unroll
    for (int ks = 0; ks < 4; ++ks) {
        short8 a = *reinterpret_cast<const short8*>(shid + (w * 16 + lr) * HSTRIDE + ks * 32 + kg * 8);
#pragma unroll
        for (int n = 0; n < 4; ++n) {
            short8 b = *reinterpret_cast<const short8*>(w2t + (n * 16 + lr) * 128 + ks * 32 + kg * 8);
            acc2[n] = __builtin_amdgcn_mfma_f32_16x16x32_bf16(a, b, acc2[n], 0, 0, 0);
        }
    }

    float v[4][4];
    float ss[4];
#pragma unroll
    for (int q = 0; q < 4; ++q) ss[q] = 0.f;
#pragma unroll
    for (int n = 0; n < 4; ++n) {
        float bv = b2[n * 16 + lr];
#pragma unroll
        for (int q = 0; q < 4; ++q) {
            float x = acc2[n][q] + bv;
            v[n][q] = x;
            ss[q] += x * x;
        }
    }
#pragma unroll
    for (int q = 0; q < 4; ++q) {
#pragma unroll
        for (int d = 1; d < 16; d <<= 1) ss[q] += __shfl_xor(ss[q], d);
    }
#pragma unroll
    for (int q = 0; q < 4; ++q) {
        int node = row_base + kg * 4 + q;
        if (node < N_NODES) {
            float scale = 1.f / fmaxf(sqrtf(ss[q]), 1e-12f);
#pragma unroll
            for (int n = 0; n < 4; ++n)
                out[(size_t)node * 64 + n * 16 + lr] = v[n][q] * scale;
        }
    }
}

extern "C" void kernel_launch(void* const* d_in, const int* in_sizes, int n_in,
                              void* d_out, int out_size, void* d_ws, size_t ws_size,
                              hipStream_t stream) {
    const float* x   = (const float*)d_in[0];
    const float* kdd = (const float*)d_in[1];
    const float* kda = (const float*)d_in[2];
    const float* l0w = (const float*)d_in[3];
    const float* l0b = (const float*)d_in[4];
    const float* w1  = (const float*)d_in[5];
    const float* b1  = (const float*)d_in[6];
    const float* w2  = (const float*)d_in[7];
    const float* b2  = (const float*)d_in[8];
    const int*   src = (const int*)d_in[9];
    const int*   dst = (const int*)d_in[10];
    float* out = (float*)d_out;
    char* ws = (char*)d_ws;

    // workspace layout (bytes):
    //   rp    [0, +400004)
    //   w0t   [400384, +10240)        bf16 80x64
    //   w1t   [410624, +40960)        bf16 128x160
    //   w2t   [451584, +16384)        bf16 64x128
    //   hcb   [475136, +4.0 MB)       bf16 N*20
    //   h3b   [4480000, +12.80 MB)    bf16 100032*64 (K-padded)
    //   h4b   [17284096, +14.4 MB)    bf16 N*72
    int*   rp  = (int*)ws;
    unsigned short* w0t = (unsigned short*)(ws + 400384u);
    unsigned short* w1t = (unsigned short*)(ws + 410624u);
    unsigned short* w2t = (unsigned short*)(ws + 451584u);
    unsigned short* hcb = (unsigned short*)(ws + 475136u);
    unsigned short* h3b = (unsigned short*)(ws + 4480000u);
    unsigned short* h4b = (unsigned short*)(ws + 17284096u);

    rowptr_k<<<(N_NODES + 1 + 255) / 256, 256, 0, stream>>>(dst, rp);
    prep_k<<<(128 * 160 + 64 * 128 + 80 * 64 + 255) / 256, 256, 0, stream>>>(w1, w2, l0w, w1t, w2t, w0t);

    // DD phase: x[N,3] -> h1 (hcb cols 0:6) -> h2 (hcb cols 6:18)
    conv1_k<20><<<(N_NODES * 3 + 255) / 256, 256, 0, stream>>>(x, kdd, src, rp, hcb);
    convb_k<6, 2, 20, 20, 6, 0, 0><<<(N_NODES * 3 + 255) / 256, 256, 0, stream>>>(hcb, kdd, src, rp, hcb);

    // DA phase
    convb_k<18, 2, 20, 64, 0, 36, 64><<<(N_NODES * 9 + 255) / 256, 256, 0, stream>>>(hcb, kda, src, rp, h3b);
    lin0m_k<<<(N_NODES + 63) / 64, 256, 0, stream>>>(h3b, w0t, l0b, h4b);

    // fused conv4 + MLP head + normalize
    fused_k<<<(N_NODES + 63) / 64, 256, 0, stream>>>(h4b, kda, src, rp, w1t, b1, w2t, b2, out);
}

// Round 7
// 193.306 us; speedup vs baseline: 1.0705x; 1.0705x over previous
//
#include <hip/hip_runtime.h>

#define N_NODES 100000
#define N_EDGES 1600000

typedef __attribute__((ext_vector_type(8))) short short8;
typedef __attribute__((ext_vector_type(4))) float f32x4;
typedef __attribute__((ext_vector_type(2))) unsigned short ushort2v;
typedef __attribute__((ext_vector_type(4))) unsigned short ushort4v;
typedef __attribute__((ext_vector_type(8))) unsigned short ushort8v;

static __device__ inline unsigned short f2bf(float f) {
    union { float f; unsigned u; } v; v.f = f;
    unsigned r = v.u + 0x7FFF + ((v.u >> 16) & 1);   // round-to-nearest-even
    return (unsigned short)(r >> 16);
}
static __device__ inline float bf2f(unsigned short u) {
    union { unsigned u; float f; } v; v.u = ((unsigned)u) << 16;
    return v.f;
}

// ---------------- row_ptr via binary search over sorted dst ----------------
__global__ __launch_bounds__(256) void rowptr_k(const int* __restrict__ dst,
                                                int* __restrict__ rp) {
    int t = blockIdx.x * blockDim.x + threadIdx.x;
    if (t > N_NODES) return;
    int lo = 0, hi = N_EDGES;
    while (lo < hi) {
        int mid = (lo + hi) >> 1;
        if (dst[mid] < t) lo = mid + 1; else hi = mid;
    }
    rp[t] = lo;
}

// ---------------- weight prep: transpose + bf16 ----------------------------
__global__ __launch_bounds__(256) void prep_k(const float* __restrict__ w1,
                                              const float* __restrict__ w2,
                                              const float* __restrict__ l0w,
                                              unsigned short* __restrict__ w1t,
                                              unsigned short* __restrict__ w2t,
                                              unsigned short* __restrict__ w0t) {
    int id = blockIdx.x * blockDim.x + threadIdx.x;
    if (id < 128 * 160) {
        int o = id / 160, k = id - o * 160;
        w1t[id] = (k < 144) ? f2bf(w1[k * 128 + o]) : (unsigned short)0;
    } else if (id < 128 * 160 + 64 * 128) {
        int j = id - 128 * 160;
        int o = j / 128, k = j - o * 128;
        w2t[j] = f2bf(w2[k * 64 + o]);
    } else if (id < 128 * 160 + 64 * 128 + 80 * 64) {
        int j = id - 128 * 160 - 64 * 128;
        int o = j / 64, k = j - o * 64;
        w0t[j] = (o < 72 && k < 36) ? f2bf(l0w[k * 72 + o]) : (unsigned short)0;
    }
}

template<int VEC> struct VecU;
template<> struct VecU<1> { using T = unsigned short; };
template<> struct VecU<2> { using T = ushort2v; };
template<> struct VecU<4> { using T = ushort4v; };
template<> struct VecU<8> { using T = ushort8v; };

// ---------------- conv1: f32 in [N][3] -> bf16 out -------------------------
template<int OUT_STRIDE>
__global__ __launch_bounds__(256) void conv1_k(const float* __restrict__ hin,
                                               const float* __restrict__ kv,
                                               const int* __restrict__ src,
                                               const int* __restrict__ rp,
                                               unsigned short* __restrict__ hout) {
    int id = blockIdx.x * blockDim.x + threadIdx.x;
    if (id >= N_NODES * 3) return;
    int t = id / 3;
    int c = id - t * 3;
    int e0 = rp[t], e1 = rp[t + 1];
    float a0 = 0.f, a1 = 0.f;
    int e = e0;
    for (; e + 8 <= e1; e += 8) {
        int s[8]; float k0[8], k1[8], v[8];
#pragma unroll
        for (int u = 0; u < 8; ++u) s[u]  = src[e + u];
#pragma unroll
        for (int u = 0; u < 8; ++u) k0[u] = kv[e + u];
#pragma unroll
        for (int u = 0; u < 8; ++u) k1[u] = kv[N_EDGES + e + u];
#pragma unroll
        for (int u = 0; u < 8; ++u) v[u]  = hin[(size_t)s[u] * 3 + c];
#pragma unroll
        for (int u = 0; u < 8; ++u) { a0 += k0[u] * v[u]; a1 += k1[u] * v[u]; }
    }
    for (; e < e1; ++e) {
        int s = src[e];
        float v = hin[(size_t)s * 3 + c];
        a0 += kv[e] * v;
        a1 += kv[N_EDGES + e] * v;
    }
    hout[(size_t)t * OUT_STRIDE + c]     = f2bf(a0);
    hout[(size_t)t * OUT_STRIDE + 3 + c] = f2bf(a1);
}

// ---------------- bf16 aniso conv (conv2/conv3) ----------------------------
template<int C, int VEC, int IN_STRIDE, int OUT_STRIDE, int OUT_OFF,
         int PAD_FROM, int PAD_TO>
__global__ __launch_bounds__(256) void convb_k(const unsigned short* __restrict__ hin,
                                               const float* __restrict__ kv,
                                               const int* __restrict__ src,
                                               const int* __restrict__ rp,
                                               unsigned short* __restrict__ hout) {
    constexpr int G = C / VEC;
    using VT = typename VecU<VEC>::T;
    int id = blockIdx.x * blockDim.x + threadIdx.x;
    if (id >= N_NODES * G) return;
    int t = id / G;
    int g = id - t * G;
    int c0 = g * VEC;
    int e0 = rp[t], e1 = rp[t + 1];

    float a0[VEC], a1[VEC];
#pragma unroll
    for (int q = 0; q < VEC; ++q) { a0[q] = 0.f; a1[q] = 0.f; }

    int e = e0;
    for (; e + 8 <= e1; e += 8) {
        int s[8]; float k0[8], k1[8];
#pragma unroll
        for (int u = 0; u < 8; ++u) s[u]  = src[e + u];
#pragma unroll
        for (int u = 0; u < 8; ++u) k0[u] = kv[e + u];
#pragma unroll
        for (int u = 0; u < 8; ++u) k1[u] = kv[N_EDGES + e + u];
        VT v[8];
#pragma unroll
        for (int u = 0; u < 8; ++u)
            v[u] = *reinterpret_cast<const VT*>(hin + (size_t)s[u] * IN_STRIDE + c0);
#pragma unroll
        for (int u = 0; u < 8; ++u) {
            const unsigned short* vf = reinterpret_cast<const unsigned short*>(&v[u]);
#pragma unroll
            for (int q = 0; q < VEC; ++q) {
                float x = bf2f(vf[q]);
                a0[q] += k0[u] * x;
                a1[q] += k1[u] * x;
            }
        }
    }
    for (; e < e1; ++e) {
        int s = src[e];
        float k0 = kv[e], k1 = kv[N_EDGES + e];
        VT v = *reinterpret_cast<const VT*>(hin + (size_t)s * IN_STRIDE + c0);
        const unsigned short* vf = reinterpret_cast<const unsigned short*>(&v);
#pragma unroll
        for (int q = 0; q < VEC; ++q) {
            float x = bf2f(vf[q]);
            a0[q] += k0 * x;
            a1[q] += k1 * x;
        }
    }

    VT r0, r1;
    unsigned short* r0f = reinterpret_cast<unsigned short*>(&r0);
    unsigned short* r1f = reinterpret_cast<unsigned short*>(&r1);
#pragma unroll
    for (int q = 0; q < VEC; ++q) { r0f[q] = f2bf(a0[q]); r1f[q] = f2bf(a1[q]); }
    *reinterpret_cast<VT*>(hout + (size_t)t * OUT_STRIDE + OUT_OFF + c0)     = r0;
    *reinterpret_cast<VT*>(hout + (size_t)t * OUT_STRIDE + OUT_OFF + C + c0) = r1;

    if constexpr (PAD_TO > PAD_FROM) {
        if (g == G - 1) {
            ushort4v z = {0, 0, 0, 0};
#pragma unroll
            for (int j = PAD_FROM; j < PAD_TO; j += 4)
                *reinterpret_cast<ushort4v*>(hout + (size_t)t * OUT_STRIDE + j) = z;
        }
    }
}

// ---------------- lin0 via MFMA: h4b = relu(h3b[N][64] @ w0t + b0) ---------
__global__ __launch_bounds__(256) void lin0m_k(const unsigned short* __restrict__ h3b,
                                               const unsigned short* __restrict__ w0t,
                                               const float* __restrict__ b0,
                                               unsigned short* __restrict__ h4b) {
    int tid = threadIdx.x;
    int w = tid >> 6;
    int lane = tid & 63;
    int lr = lane & 15;
    int kg = lane >> 4;
    int row_base = blockIdx.x * 64 + w * 16;

    f32x4 acc[5];
#pragma unroll
    for (int n = 0; n < 5; ++n) acc[n] = (f32x4){0.f, 0.f, 0.f, 0.f};

    const unsigned short* arow = h3b + (size_t)(row_base + lr) * 64 + kg * 8;
#pragma unroll
    for (int ks = 0; ks < 2; ++ks) {
        short8 a = *reinterpret_cast<const short8*>(arow + ks * 32);
#pragma unroll
        for (int n = 0; n < 5; ++n) {
            short8 b = *reinterpret_cast<const short8*>(w0t + (n * 16 + lr) * 64 + ks * 32 + kg * 8);
            acc[n] = __builtin_amdgcn_mfma_f32_16x16x32_bf16(a, b, acc[n], 0, 0, 0);
        }
    }
#pragma unroll
    for (int n = 0; n < 5; ++n) {
        int col = n * 16 + lr;
        if (col < 72) {
            float bv = b0[col];
#pragma unroll
            for (int q = 0; q < 4; ++q) {
                int t = row_base + kg * 4 + q;
                if (t < N_NODES)
                    h4b[(size_t)t * 72 + col] = f2bf(fmaxf(acc[n][q] + bv, 0.f));
            }
        }
    }
}

// ---------------- fused conv4 + MLP head + L2 normalize --------------------
// Block = 256 thr (4 waves), 64 nodes. Phase A: gather-conv into LDS tile
// [64][FH]. Phase B: preload A-frags to regs, barrier, MFMA stage1, write
// hidden back into the SAME LDS buffer (overlay, stride HST). Phase C: MFMA
// stage2 + bias + L2-normalize. LDS = 21.5 KB; launch_bounds(256,4).
#define FH 168
#define HST 136
__global__ __launch_bounds__(256, 4) void fused_k(const unsigned short* __restrict__ h4b,
                                                  const float* __restrict__ kv,
                                                  const int* __restrict__ src,
                                                  const int* __restrict__ rp,
                                                  const unsigned short* __restrict__ w1t,
                                                  const float* __restrict__ b1,
                                                  const unsigned short* __restrict__ w2t,
                                                  const float* __restrict__ b2,
                                                  float* __restrict__ out) {
    __shared__ unsigned short sh[64 * FH];
    int tid = threadIdx.x;
    int node0 = blockIdx.x * 64;

    // ---- phase A: gather conv4 into sh; 576 tasks = node*9 + g ----
    for (int task = tid; task < 576; task += 256) {
        int nd = task / 9;
        int g  = task - nd * 9;
        int t  = node0 + nd;
        int c0 = g * 8;
        int e0 = 0, e1 = 0;
        if (t < N_NODES) { e0 = rp[t]; e1 = rp[t + 1]; }

        float a0[8], a1[8];
#pragma unroll
        for (int q = 0; q < 8; ++q) { a0[q] = 0.f; a1[q] = 0.f; }

        int e = e0;
        for (; e + 8 <= e1; e += 8) {
            int s[8]; float k0[8], k1[8];
#pragma unroll
            for (int u = 0; u < 8; ++u) s[u]  = src[e + u];
#pragma unroll
            for (int u = 0; u < 8; ++u) k0[u] = kv[e + u];
#pragma unroll
            for (int u = 0; u < 8; ++u) k1[u] = kv[N_EDGES + e + u];
            ushort8v v[8];
#pragma unroll
            for (int u = 0; u < 8; ++u)
                v[u] = *reinterpret_cast<const ushort8v*>(h4b + (size_t)s[u] * 72 + c0);
#pragma unroll
            for (int u = 0; u < 8; ++u) {
#pragma unroll
                for (int q = 0; q < 8; ++q) {
                    float x = bf2f(v[u][q]);
                    a0[q] += k0[u] * x;
                    a1[q] += k1[u] * x;
                }
            }
        }
        for (; e < e1; ++e) {
            int s = src[e];
            float k0 = kv[e], k1 = kv[N_EDGES + e];
            ushort8v v = *reinterpret_cast<const ushort8v*>(h4b + (size_t)s * 72 + c0);
#pragma unroll
            for (int q = 0; q < 8; ++q) {
                float x = bf2f(v[q]);
                a0[q] += k0 * x;
                a1[q] += k1 * x;
            }
        }

        ushort8v r0, r1;
#pragma unroll
        for (int q = 0; q < 8; ++q) { r0[q] = f2bf(a0[q]); r1[q] = f2bf(a1[q]); }
        *reinterpret_cast<ushort8v*>(sh + nd * FH + c0)      = r0;
        *reinterpret_cast<ushort8v*>(sh + nd * FH + 72 + c0) = r1;
    }
    // zero K-pad cols 144..159
    for (int i = tid; i < 128; i += 256) {
        int nd = i >> 1, half = i & 1;
        ushort8v z = {0, 0, 0, 0, 0, 0, 0, 0};
        *reinterpret_cast<ushort8v*>(sh + nd * FH + 144 + half * 8) = z;
    }
    __syncthreads();

    // ---- phase B: preload A-frags, then stage-1 MFMA; overlay hidden ----
    int w = tid >> 6;
    int lane = tid & 63;
    int lr = lane & 15;
    int kg = lane >> 4;
    int row_base = node0 + w * 16;

    const unsigned short* arow = sh + (w * 16 + lr) * FH + kg * 8;
    short8 a5[5];
#pragma unroll
    for (int ks = 0; ks < 5; ++ks)
        a5[ks] = *reinterpret_cast<const short8*>(arow + ks * 32);
    __syncthreads();   // all sh reads done before overlay writes

    f32x4 acc[8];
#pragma unroll
    for (int n = 0; n < 8; ++n) acc[n] = (f32x4){0.f, 0.f, 0.f, 0.f};
#pragma unroll
    for (int ks = 0; ks < 5; ++ks) {
#pragma unroll
        for (int n = 0; n < 8; ++n) {
            short8 b = *reinterpret_cast<const short8*>(w1t + (n * 16 + lr) * 160 + ks * 32 + kg * 8);
            acc[n] = __builtin_amdgcn_mfma_f32_16x16x32_bf16(a5[ks], b, acc[n], 0, 0, 0);
        }
    }
#pragma unroll
    for (int n = 0; n < 8; ++n) {
        float bv = b1[n * 16 + lr];
#pragma unroll
        for (int q = 0; q < 4; ++q) {
            float hv = fmaxf(acc[n][q] + bv, 0.f);
            sh[(w * 16 + kg * 4 + q) * HST + n * 16 + lr] = f2bf(hv);
        }
    }
    __syncthreads();

    // ---- phase C: stage 2 MFMA + bias + normalize ----
    f32x4 acc2[4];
#pragma unroll
    for (int n = 0; n < 4; ++n) acc2[n] = (f32x4){0.f, 0.f, 0.f, 0.f};
#pragma unroll
    for (int ks = 0; ks < 4; ++ks) {
        short8 a = *reinterpret_cast<const short8*>(sh + (w * 16 + lr) * HST + ks * 32 + kg * 8);
#pragma unroll
        for (int n = 0; n < 4; ++n) {
            short8 b = *reinterpret_cast<const short8*>(w2t + (n * 16 + lr) * 128 + ks * 32 + kg * 8);
            acc2[n] = __builtin_amdgcn_mfma_f32_16x16x32_bf16(a, b, acc2[n], 0, 0, 0);
        }
    }

    float v[4][4];
    float ss[4];
#pragma unroll
    for (int q = 0; q < 4; ++q) ss[q] = 0.f;
#pragma unroll
    for (int n = 0; n < 4; ++n) {
        float bv = b2[n * 16 + lr];
#pragma unroll
        for (int q = 0; q < 4; ++q) {
            float x = acc2[n][q] + bv;
            v[n][q] = x;
            ss[q] += x * x;
        }
    }
#pragma unroll
    for (int q = 0; q < 4; ++q) {
#pragma unroll
        for (int d = 1; d < 16; d <<= 1) ss[q] += __shfl_xor(ss[q], d);
    }
#pragma unroll
    for (int q = 0; q < 4; ++q) {
        int node = row_base + kg * 4 + q;
        if (node < N_NODES) {
            float scale = 1.f / fmaxf(sqrtf(ss[q]), 1e-12f);
#pragma unroll
            for (int n = 0; n < 4; ++n)
                out[(size_t)node * 64 + n * 16 + lr] = v[n][q] * scale;
        }
    }
}

extern "C" void kernel_launch(void* const* d_in, const int* in_sizes, int n_in,
                              void* d_out, int out_size, void* d_ws, size_t ws_size,
                              hipStream_t stream) {
    const float* x   = (const float*)d_in[0];
    const float* kdd = (const float*)d_in[1];
    const float* kda = (const float*)d_in[2];
    const float* l0w = (const float*)d_in[3];
    const float* l0b = (const float*)d_in[4];
    const float* w1  = (const float*)d_in[5];
    const float* b1  = (const float*)d_in[6];
    const float* w2  = (const float*)d_in[7];
    const float* b2  = (const float*)d_in[8];
    const int*   src = (const int*)d_in[9];
    const int*   dst = (const int*)d_in[10];
    float* out = (float*)d_out;
    char* ws = (char*)d_ws;

    // workspace layout (bytes):
    //   rp    [0, +400004)
    //   w0t   [400384, +10240)        bf16 80x64
    //   w1t   [410624, +40960)        bf16 128x160
    //   w2t   [451584, +16384)        bf16 64x128
    //   hcb   [475136, +4.0 MB)       bf16 N*20
    //   h3b   [4480000, +12.80 MB)    bf16 100032*64 (K-padded)
    //   h4b   [17284096, +14.4 MB)    bf16 N*72
    int*   rp  = (int*)ws;
    unsigned short* w0t = (unsigned short*)(ws + 400384u);
    unsigned short* w1t = (unsigned short*)(ws + 410624u);
    unsigned short* w2t = (unsigned short*)(ws + 451584u);
    unsigned short* hcb = (unsigned short*)(ws + 475136u);
    unsigned short* h3b = (unsigned short*)(ws + 4480000u);
    unsigned short* h4b = (unsigned short*)(ws + 17284096u);

    rowptr_k<<<(N_NODES + 1 + 255) / 256, 256, 0, stream>>>(dst, rp);
    prep_k<<<(128 * 160 + 64 * 128 + 80 * 64 + 255) / 256, 256, 0, stream>>>(w1, w2, l0w, w1t, w2t, w0t);

    // DD phase: x[N,3] -> h1 (hcb cols 0:6) -> h2 (hcb cols 6:18)
    conv1_k<20><<<(N_NODES * 3 + 255) / 256, 256, 0, stream>>>(x, kdd, src, rp, hcb);
    convb_k<6, 2, 20, 20, 6, 0, 0><<<(N_NODES * 3 + 255) / 256, 256, 0, stream>>>(hcb, kdd, src, rp, hcb);

    // DA phase
    convb_k<18, 2, 20, 64, 0, 36, 64><<<(N_NODES * 9 + 255) / 256, 256, 0, stream>>>(hcb, kda, src, rp, h3b);
    lin0m_k<<<(N_NODES + 63) / 64, 256, 0, stream>>>(h3b, w0t, l0b, h4b);

    // fused conv4 + MLP head + normalize
    fused_k<<<(N_NODES + 63) / 64, 256, 0, stream>>>(h4b, kda, src, rp, w1t, b1, w2t, b2, out);
}